// Round 3
// baseline (884.852 us; speedup 1.0000x reference)
//
#include <hip/hip_runtime.h>
#include <math.h>

#define HW 100
#define FIN 128
#define NC 8        // accumulator replicas (≈ XCD count)

// ---------------- zero replicas + accums ----------------
__global__ void k_zero(float* __restrict__ copies, int n8, float* __restrict__ accums) {
    int i = blockIdx.x * blockDim.x + threadIdx.x;
    int st = gridDim.x * blockDim.x;
    for (; i < n8; i += st) copies[i] = 0.f;
    if (blockIdx.x == 0 && threadIdx.x == 0) { accums[0] = 0.f; accums[1] = 0.f; }
}

// ---------------- degree count into int replicas ----------------
__global__ __launch_bounds__(256) void k_deg(const int* __restrict__ dst, int E,
                                             int* __restrict__ icopies, int N) {
    int cb = (blockIdx.x & (NC - 1)) * N;
    int i = blockIdx.x * blockDim.x + threadIdx.x;
    int st = gridDim.x * blockDim.x;
    for (; i < E; i += st) atomicAdd(&icopies[cb + dst[i]], 1);
}

// ---------------- dinv = rsqrt(deg+1); re-zero replicas ----------------
__global__ void k_dinv(int* __restrict__ icopies, float* __restrict__ dinv, int N) {
    int i = blockIdx.x * blockDim.x + threadIdx.x;
    if (i >= N) return;
    int s = 0;
    #pragma unroll
    for (int c = 0; c < NC; ++c) { s += icopies[c * N + i]; icopies[c * N + i] = 0; }
    dinv[i] = rsqrtf((float)s + 1.0f);
}

// ---------------- weight-chain collapse (verified round 2) ----------------
__global__ void k_chain(const float* __restrict__ W1, const float* __restrict__ b1,
                        const float* __restrict__ Wh, const float* __restrict__ bh,
                        const float* __restrict__ fc1W, const float* __restrict__ fc1b,
                        const float* __restrict__ fc2W, const float* __restrict__ fc2b,
                        float* __restrict__ wstar, float* __restrict__ gammas) {
    __shared__ float v[HW], vn[HW];
    int t = threadIdx.x;
    if (t < HW) v[t] = fc2W[t];
    __syncthreads();
    if (t < HW) { float a = 0.f; for (int c = 0; c < HW; ++c) a += fc1W[t * HW + c] * v[c]; vn[t] = a; }
    __syncthreads();
    if (t < HW) v[t] = vn[t];
    __syncthreads();
    if (t == 0) {
        float a = 0.f; for (int c = 0; c < HW; ++c) a += bh[7 * HW + c] * v[c];
        float b = 0.f; for (int c = 0; c < HW; ++c) b += fc1b[c] * fc2W[c];
        gammas[9] = a + b + fc2b[0];
    }
    __syncthreads();
    for (int i = 7; i >= 0; --i) {
        const float* M = Wh + (size_t)i * HW * HW;
        if (t < HW) { float a = 0.f; for (int c = 0; c < HW; ++c) a += M[t * HW + c] * v[c]; vn[t] = a; }
        __syncthreads();
        if (t < HW) v[t] = vn[t];
        __syncthreads();
        if (t == 0) {
            const float* bb = (i >= 1) ? (bh + (size_t)(i - 1) * HW) : b1;
            float a = 0.f; for (int c = 0; c < HW; ++c) a += bb[c] * v[c];
            gammas[i + 1] = a;
        }
        __syncthreads();
    }
    { float a = 0.f; for (int c = 0; c < HW; ++c) a += W1[t * HW + c] * v[c]; wstar[t] = a; }
}

// ---------------- u0 = dinv * (x @ wstar)  (wave per row) ----------------
__global__ __launch_bounds__(256) void k_gemv(const float* __restrict__ x,
                                              const float* __restrict__ wstar,
                                              const float* __restrict__ dinv,
                                              float* __restrict__ u, int n) {
    __shared__ float ws[FIN];
    int tid = threadIdx.x;
    if (tid < FIN) ws[tid] = wstar[tid];
    __syncthreads();
    int node = blockIdx.x * 4 + (tid >> 6);
    int lane = tid & 63;
    if (node >= n) return;
    const float* xr = x + (size_t)node * FIN;
    float2 a = *reinterpret_cast<const float2*>(&xr[lane * 2]);
    float v = a.x * ws[lane * 2] + a.y * ws[lane * 2 + 1];
    #pragma unroll
    for (int off = 32; off; off >>= 1) v += __shfl_down(v, off);
    if (lane == 0) u[node] = v * dinv[node];
}

// ---------------- edge scatter: copies[c][dst] += u[src] ----------------
__global__ __launch_bounds__(256) void k_scatter(const int* __restrict__ src,
                                                 const int* __restrict__ dst, int E,
                                                 const float* __restrict__ u,
                                                 float* __restrict__ copies, int N) {
    int cb = (blockIdx.x & (NC - 1)) * N;
    int i = blockIdx.x * blockDim.x + threadIdx.x;
    int st = gridDim.x * blockDim.x;
    for (; i < E; i += st)
        unsafeAtomicAdd(&copies[cb + dst[i]], u[src[i]]);
}

// ---------------- reduce replicas: y = dinv*(sum + u_old) + gamma; u_new = dinv*y ----
__global__ void k_reduce(float* __restrict__ copies, const float* __restrict__ dinv,
                         const float* __restrict__ uold, const float* __restrict__ gammas,
                         int k, float* __restrict__ ybuf, float* __restrict__ unew, int N) {
    int i = blockIdx.x * blockDim.x + threadIdx.x;
    if (i >= N) return;
    float s = 0.f;
    #pragma unroll
    for (int c = 0; c < NC; ++c) { s += copies[c * N + i]; copies[c * N + i] = 0.f; }
    float di = dinv[i];
    float y = di * (s + uold[i]) + gammas[k];
    ybuf[i] = y;
    unew[i] = di * y;
}

// ---------------- pos = sum(labels) ----------------
__global__ void k_pos(const float* __restrict__ labels, int n, float* __restrict__ accums) {
    __shared__ float s[256];
    float v = 0.f;
    for (int i = blockIdx.x * blockDim.x + threadIdx.x; i < n; i += gridDim.x * blockDim.x)
        v += labels[i];
    s[threadIdx.x] = v; __syncthreads();
    for (int off = 128; off; off >>= 1) {
        if (threadIdx.x < off) s[threadIdx.x] += s[threadIdx.x + off];
        __syncthreads();
    }
    if (threadIdx.x == 0) atomicAdd(&accums[0], s[0]);
}

// ---------------- sigmoid + weighted BCE ----------------
__global__ __launch_bounds__(256) void k_loss(const float* __restrict__ L,
                                              const float* __restrict__ labels,
                                              const float* __restrict__ accums,
                                              float* __restrict__ out_p,
                                              float* __restrict__ loss_accum, int n) {
    __shared__ float s[256];
    float pos = accums[0];
    float wpos = ((float)n - pos) / pos;
    float acc = 0.f;
    for (int i = blockIdx.x * blockDim.x + threadIdx.x; i < n; i += gridDim.x * blockDim.x) {
        float logit = L[i];
        float p = 1.f / (1.f + expf(-logit));
        out_p[i] = p;
        float pc = fminf(fmaxf(p, 1e-7f), 1.f - 1e-7f);
        float l = labels[i];
        float w = wpos * l + 1.f;
        acc += w * (-(l * logf(pc) + (1.f - l) * logf(1.f - pc)));
    }
    s[threadIdx.x] = acc; __syncthreads();
    for (int off = 128; off; off >>= 1) {
        if (threadIdx.x < off) s[threadIdx.x] += s[threadIdx.x + off];
        __syncthreads();
    }
    if (threadIdx.x == 0) atomicAdd(loss_accum, s[0]);
}

__global__ void k_final(const float* __restrict__ accums, float* __restrict__ out0, int n) {
    if (blockIdx.x == 0 && threadIdx.x == 0) out0[0] = accums[1] / (float)n;
}

// ---------------- launch ----------------
extern "C" void kernel_launch(void* const* d_in, const int* in_sizes, int n_in,
                              void* d_out, int out_size, void* d_ws, size_t ws_size,
                              hipStream_t stream) {
    const float* x      = (const float*)d_in[0];
    const int*   edge   = (const int*)d_in[1];
    const float* labels = (const float*)d_in[2];
    const float* W1     = (const float*)d_in[3];
    const float* b1     = (const float*)d_in[4];
    const float* Wh     = (const float*)d_in[5];
    const float* bh     = (const float*)d_in[6];
    const float* fc1W   = (const float*)d_in[7];
    const float* fc1b   = (const float*)d_in[8];
    const float* fc2W   = (const float*)d_in[9];
    const float* fc2b   = (const float*)d_in[10];

    const int N = in_sizes[0] / FIN;   // 100000
    const int E = in_sizes[1] / 2;     // 1600000
    const int* srcIdx = edge;
    const int* dstIdx = edge + E;

    size_t o = 0;
    auto carve = [&](size_t bytes) {
        void* p = (char*)d_ws + o;
        o += (bytes + 511) & ~(size_t)511;
        return p;
    };
    float* copies = (float*)carve((size_t)NC * N * 4);
    float* dinv   = (float*)carve((size_t)N * 4);
    float* ua     = (float*)carve((size_t)N * 4);
    float* ub     = (float*)carve((size_t)N * 4);
    float* ybuf   = (float*)carve((size_t)N * 4);
    float* accums = (float*)carve(2 * 4);
    float* wstar  = (float*)carve(FIN * 4);
    float* gammas = (float*)carve(16 * 4);
    (void)ws_size; (void)n_in; (void)out_size;

    const int SCAT_BLOCKS = 1024;   // multiple of NC; identical grid each pass -> L2 reuse

    k_zero<<<512, 256, 0, stream>>>(copies, NC * N, accums);
    k_deg<<<SCAT_BLOCKS, 256, 0, stream>>>(dstIdx, E, (int*)copies, N);
    k_dinv<<<(N + 255) / 256, 256, 0, stream>>>((int*)copies, dinv, N);
    k_pos<<<256, 256, 0, stream>>>(labels, N, accums);
    k_chain<<<1, FIN, 0, stream>>>(W1, b1, Wh, bh, fc1W, fc1b, fc2W, fc2b, wstar, gammas);

    k_gemv<<<(N + 3) / 4, 256, 0, stream>>>(x, wstar, dinv, ua, N);

    float* uo = ua; float* un = ub;
    for (int k = 1; k <= 9; ++k) {
        k_scatter<<<SCAT_BLOCKS, 256, 0, stream>>>(srcIdx, dstIdx, E, uo, copies, N);
        k_reduce<<<(N + 255) / 256, 256, 0, stream>>>(copies, dinv, uo, gammas, k, ybuf, un, N);
        float* t = uo; uo = un; un = t;
    }

    float* outF = (float*)d_out;
    k_loss<<<512, 256, 0, stream>>>(ybuf, labels, accums, outF + 1, accums + 1, N);
    k_final<<<1, 64, 0, stream>>>(accums, outF, N);
}